// Round 4
// baseline (913.764 us; speedup 1.0000x reference)
//
#include <hip/hip_runtime.h>
#include <cstdint>
#include <cstddef>

// Problem constants
#define B_DIM  8192
#define H_DIM  2048
#define LDA    6144      // A buffer column stride: [h | x | rh]
#define LDB    4096      // B buffers column stride (K=4096 concatenated)

typedef __attribute__((ext_vector_type(8))) short  short8;   // 8 x bf16 (4 VGPRs)
typedef __attribute__((ext_vector_type(4))) float  float4v;  // MFMA accumulator

__device__ __forceinline__ unsigned short f2bf(float f) {
    union { float f; unsigned u; } v; v.f = f;
    unsigned r = v.u + 0x7fffu + ((v.u >> 16) & 1u);  // RNE
    return (unsigned short)(r >> 16);
}

__device__ __forceinline__ float sigmoidf_(float x) {
    return 1.0f / (1.0f + __expf(-x));
}

// ---------------------------------------------------------------------------
// fp32 -> bf16 conversion of x_t / h_prev into the fused A buffer.
// ---------------------------------------------------------------------------
__global__ void cvt_rows(const float* __restrict__ x, const float* __restrict__ h,
                         unsigned short* __restrict__ Abuf) {
    const float* s = blockIdx.z ? h : x;
    const int coff = blockIdx.z ? 0 : 2048;
    const int row = blockIdx.x;
    const int c = threadIdx.x * 8;
    float4 a = *(const float4*)(s + (size_t)row * 2048 + c);
    float4 b = *(const float4*)(s + (size_t)row * 2048 + c + 4);
    union { unsigned short us[8]; uint4 u4; } o;
    o.us[0] = f2bf(a.x); o.us[1] = f2bf(a.y); o.us[2] = f2bf(a.z); o.us[3] = f2bf(a.w);
    o.us[4] = f2bf(b.x); o.us[5] = f2bf(b.y); o.us[6] = f2bf(b.z); o.us[7] = f2bf(b.w);
    *(uint4*)(Abuf + (size_t)row * LDA + coff + c) = o.u4;
}

// ---------------------------------------------------------------------------
// Transpose + convert: src fp32 [2048 k][2048 n] -> dst bf16 [n][k].
// ---------------------------------------------------------------------------
struct P6 { const float* s[6]; unsigned short* d[6]; };

__global__ void transpose_cvt(P6 io) {
    __shared__ float tile[64][65];
    const float* src = io.s[blockIdx.z];
    unsigned short* dst = io.d[blockIdx.z];
    const int n0 = blockIdx.x * 64;
    const int k0 = blockIdx.y * 64;
    const int t = threadIdx.x;
#pragma unroll
    for (int p = 0; p < 4; ++p) {
        const int k = p * 16 + (t >> 4);
        const int n4 = (t & 15) * 4;
        float4 v = *(const float4*)(src + (size_t)(k0 + k) * 2048 + n0 + n4);
        tile[n4 + 0][k] = v.x; tile[n4 + 1][k] = v.y;
        tile[n4 + 2][k] = v.z; tile[n4 + 3][k] = v.w;
    }
    __syncthreads();
#pragma unroll
    for (int p = 0; p < 2; ++p) {
        const int n = p * 32 + (t >> 3);
        const int k8 = (t & 7) * 8;
        union { unsigned short us[8]; uint4 u4; } o;
#pragma unroll
        for (int q = 0; q < 8; ++q) o.us[q] = f2bf(tile[n][k8 + q]);
        *(uint4*)(dst + (size_t)(n0 + n) * LDB + k0 + k8) = o.u4;
    }
}

// ---------------------------------------------------------------------------
// GEMM core: 128x128 tile, BK=32, 16x16x32 bf16 MFMA, 4x4 acc/wave, XOR-swizzle
// (0 bank conflicts). Register-pipelined staging (AITER-style): global loads go
// to VGPRs (NOT drained at barriers), ds_write consumes them one iteration
// later -> vmcnt stays >0 across barriers, loads in flight during compute.
// ---------------------------------------------------------------------------
struct Tile { short8 a0, a1, b0, b1; };

__device__ __forceinline__ Tile load_tile(const unsigned short* Ab,
                                          const unsigned short* Bb, int k0) {
    Tile r;
    r.a0 = *(const short8*)(Ab + k0);
    r.a1 = *(const short8*)(Ab + (size_t)64 * LDA + k0);
    r.b0 = *(const short8*)(Bb + k0);
    r.b1 = *(const short8*)(Bb + (size_t)64 * LDB + k0);
    return r;
}

__device__ __forceinline__ void write_tile(unsigned short* buf, int t, const Tile& x) {
    *(short8*)(buf + t * 8)        = x.a0;
    *(short8*)(buf + 2048 + t * 8) = x.a1;
    *(short8*)(buf + 4096 + t * 8) = x.b0;
    *(short8*)(buf + 6144 + t * 8) = x.b1;
}

__device__ __forceinline__ void compute_tile(const unsigned short* buf,
                                             int wm, int wn, int fr, int fsw,
                                             float4v (&acc)[4][4]) {
    short8 af[4], bfr[4];
#pragma unroll
    for (int i = 0; i < 4; ++i)
        af[i] = *(const short8*)(buf + (wm * 64 + i * 16 + fr) * 32 + fsw);
#pragma unroll
    for (int j = 0; j < 4; ++j)
        bfr[j] = *(const short8*)(buf + 4096 + (wn * 64 + j * 16 + fr) * 32 + fsw);
#pragma unroll
    for (int i = 0; i < 4; ++i)
#pragma unroll
        for (int j = 0; j < 4; ++j)
            acc[i][j] = __builtin_amdgcn_mfma_f32_16x16x32_bf16(af[i], bfr[j], acc[i][j], 0, 0, 0);
}

__device__ __forceinline__ void gemm_core(const unsigned short* __restrict__ A,
                                          const unsigned short* __restrict__ Bt,
                                          int m0, int n0,
                                          float4v (&acc)[4][4],
                                          unsigned short* lds) {
    const int t    = threadIdx.x;
    const int lane = t & 63;
    const int wm   = (t >> 6) >> 1;
    const int wn   = (t >> 6) & 1;
    const int row  = t >> 2;                                  // staging row 0..63
    const int sseg = ((t & 3) ^ ((t >> 3) & 3)) * 8;          // swizzled k-seg (elems)
    const int fr   = lane & 15;
    const int fsw  = (((lane >> 4) ^ ((fr >> 1) & 3))) * 8;   // swizzled frag k-offset

    const unsigned short* Ab = A  + (size_t)(m0 + row) * LDA + sseg;
    const unsigned short* Bb = Bt + (size_t)(n0 + row) * LDB + sseg;
    unsigned short* buf0 = lds;
    unsigned short* buf1 = lds + 8192;

    Tile r = load_tile(Ab, Bb, 0);
    write_tile(buf0, t, r);                 // vmcnt wait on r here (prologue only)
    r = load_tile(Ab, Bb, 32);              // tile 1 in flight across the barrier
    __syncthreads();                        // publishes buf0

    for (int p = 0; p < 64; ++p) {
        // --- even step: buf0 holds tile 2p, r holds tile 2p+1 ---
        {
            int kb = 2 * p + 2; if (kb > 127) kb = 127;   // clamped dummy at tail
            write_tile(buf1, t, r);         // waits vmcnt for r (1 iter old)
            r = load_tile(Ab, Bb, kb * 32); // tile 2p+2, stays in flight
            compute_tile(buf0, wm, wn, fr, fsw, acc);
            __syncthreads();                // lgkm drain only; vmcnt stays >0
        }
        // --- odd step: buf1 holds tile 2p+1, r holds tile 2p+2 ---
        {
            int kb = 2 * p + 3; if (kb > 127) kb = 127;
            write_tile(buf0, t, r);
            r = load_tile(Ab, Bb, kb * 32);
            compute_tile(buf1, wm, wn, fr, fsw, acc);
            __syncthreads();
        }
    }
}

// ---------------------------------------------------------------------------
// GEMM 1: A(k-window [h|x]) @ Bzr([Uz;Wz] | [Ur;Wr]) -> z (fp32) to d_out,
// r*h_prev (bf16) into A's rh column block. 2048 blocks, swizzled decode:
// within each 256-block supertile, id%8 fixes the m-tile per XCD (A-panel
// locality in that XCD's L2), n spans all 32 tiles (B via L3).
// ---------------------------------------------------------------------------
__global__ __launch_bounds__(256) void gemm_zr(const unsigned short* __restrict__ Abuf,
                                               const unsigned short* __restrict__ Bzr,
                                               const float* __restrict__ hprev,
                                               const float* __restrict__ bz,
                                               const float* __restrict__ br,
                                               float* __restrict__ zout,
                                               unsigned short* __restrict__ Arh) {
    __shared__ unsigned short lds[4 * 128 * 32];   // 2 x (A 8KB + B 8KB)
    float4v acc[4][4];
#pragma unroll
    for (int i = 0; i < 4; ++i)
#pragma unroll
        for (int j = 0; j < 4; ++j)
            acc[i][j] = (float4v){0.f, 0.f, 0.f, 0.f};

    const int id = blockIdx.x;
    const int m0 = (((id & 7) | ((id >> 8) << 3))) * 128;   // 64 m-tiles
    const int n0 = ((id >> 3) & 31) * 128;                  // 32 n-tiles

    gemm_core(Abuf, Bzr, m0, n0, acc, lds); // K = 4096 = [h | x]

    const int t = threadIdx.x, lane = t & 63;
    const int wm = (t >> 6) >> 1, wn = (t >> 6) & 1;
    const int col = lane & 15, rbase = (lane >> 4) * 4;
    const bool zhalf = n0 < 2048;
#pragma unroll
    for (int i = 0; i < 4; ++i)
#pragma unroll
        for (int j = 0; j < 4; ++j) {
            const int gn = n0 + wn * 64 + j * 16 + col;
            const int gm0 = m0 + wm * 64 + i * 16 + rbase;
            if (zhalf) {
                const float bias = bz[gn];
#pragma unroll
                for (int r = 0; r < 4; ++r) {
                    const size_t idx = (size_t)(gm0 + r) * H_DIM + gn;
                    zout[idx] = sigmoidf_(acc[i][j][r] + bias);
                }
            } else {
                const int gn2 = gn - 2048;
                const float bias = br[gn2];
#pragma unroll
                for (int r = 0; r < 4; ++r) {
                    const size_t idx = (size_t)(gm0 + r) * H_DIM + gn2;
                    const float rt = sigmoidf_(acc[i][j][r] + bias);
                    Arh[(size_t)(gm0 + r) * LDA + gn2] = f2bf(rt * hprev[idx]);
                }
            }
        }
}

// ---------------------------------------------------------------------------
// GEMM 2: A(k-window [x|rh]) @ Bh([Wh;Uh]) -> h_t = (1-z)h + z*tanh(.+bh).
// 1024 blocks, swizzled decode (16 n-tiles).
// ---------------------------------------------------------------------------
__global__ __launch_bounds__(256) void gemm_h(const unsigned short* __restrict__ Axrh,
                                              const unsigned short* __restrict__ Bh,
                                              const float* __restrict__ hprev,
                                              const float* __restrict__ bh,
                                              float* __restrict__ out) {
    __shared__ unsigned short lds[4 * 128 * 32];
    float4v acc[4][4];
#pragma unroll
    for (int i = 0; i < 4; ++i)
#pragma unroll
        for (int j = 0; j < 4; ++j)
            acc[i][j] = (float4v){0.f, 0.f, 0.f, 0.f};

    const int id = blockIdx.x;
    const int m0 = (((id & 7) | ((id >> 7) << 3))) * 128;   // 64 m-tiles
    const int n0 = ((id >> 3) & 15) * 128;                  // 16 n-tiles

    gemm_core(Axrh, Bh, m0, n0, acc, lds);  // K = 4096 = [x | rh]

    const int t = threadIdx.x, lane = t & 63;
    const int wm = (t >> 6) >> 1, wn = (t >> 6) & 1;
    const int col = lane & 15, rbase = (lane >> 4) * 4;
#pragma unroll
    for (int i = 0; i < 4; ++i)
#pragma unroll
        for (int j = 0; j < 4; ++j) {
            const int gn = n0 + wn * 64 + j * 16 + col;
            const int gm0 = m0 + wm * 64 + i * 16 + rbase;
            const float bias = bh[gn];
#pragma unroll
            for (int r = 0; r < 4; ++r) {
                const size_t idx = (size_t)(gm0 + r) * H_DIM + gn;
                const float ht = tanhf(acc[i][j][r] + bias);
                const float z = out[idx];     // z staged here by gemm_zr
                const float h = hprev[idx];
                out[idx] = (1.0f - z) * h + z * ht;
            }
        }
}

// ---------------------------------------------------------------------------
// Workspace (144 MiB):
//   [0,    96MiB)  A    8192 x 6144 bf16 : cols [0,2048)=h16, [2048,4096)=x16,
//                                          [4096,6144)=rh16 (filled by gemm_zr)
//   [96,  128MiB)  Bzr  4096 x 4096 bf16 : rows n:      [UzT(n)|WzT(n)]
//                                          rows 2048+n: [UrT(n)|WrT(n)]
//   [128, 144MiB)  Bh   2048 x 4096 bf16 : rows n: [WhT(n)|UhT(n)]
// ---------------------------------------------------------------------------
extern "C" void kernel_launch(void* const* d_in, const int* in_sizes, int n_in,
                              void* d_out, int out_size, void* d_ws, size_t ws_size,
                              hipStream_t stream) {
    const float* x  = (const float*)d_in[0];
    const float* h  = (const float*)d_in[1];
    const float* Wz = (const float*)d_in[2];
    const float* Wr = (const float*)d_in[3];
    const float* Wh = (const float*)d_in[4];
    const float* Uz = (const float*)d_in[5];
    const float* Ur = (const float*)d_in[6];
    const float* Uh = (const float*)d_in[7];
    const float* bz = (const float*)d_in[8];
    const float* br = (const float*)d_in[9];
    const float* bh = (const float*)d_in[10];
    float* out = (float*)d_out;

    char* ws = (char*)d_ws;
    unsigned short* Abuf = (unsigned short*)(ws);
    unsigned short* Bzr  = (unsigned short*)(ws + (size_t)96  * 1024 * 1024);
    unsigned short* Bh   = (unsigned short*)(ws + (size_t)128 * 1024 * 1024);

    // 1) convert x, h into fused A buffer
    cvt_rows<<<dim3(B_DIM, 1, 2), 256, 0, stream>>>(x, h, Abuf);

    // 2) transpose+convert weights into concatenated-K B buffers
    P6 io;
    io.s[0] = Uz; io.d[0] = Bzr;                                   // rows 0..2047, k 0..2047
    io.s[1] = Wz; io.d[1] = Bzr + 2048;                            // rows 0..2047, k 2048..4095
    io.s[2] = Ur; io.d[2] = Bzr + (size_t)2048 * LDB;              // rows 2048..4095
    io.s[3] = Wr; io.d[3] = Bzr + (size_t)2048 * LDB + 2048;
    io.s[4] = Wh; io.d[4] = Bh;
    io.s[5] = Uh; io.d[5] = Bh + 2048;
    transpose_cvt<<<dim3(32, 32, 6), 256, 0, stream>>>(io);

    // 3) z/r GEMM: M=8192, N=4096, K=4096
    gemm_zr<<<2048, 256, 0, stream>>>(Abuf, Bzr, h, bz, br, out,
                                      Abuf + 4096 /* rh col block */);

    // 4) candidate GEMM + final gate: M=8192, N=2048, K=4096
    gemm_h<<<1024, 256, 0, stream>>>(Abuf + 2048 /* [x|rh] window */,
                                     Bh, h, bh, out);
}